// Round 1
// baseline (812.819 us; speedup 1.0000x reference)
//
#include <hip/hip_runtime.h>
#include <hip/hip_bf16.h>

#define NNODES 100000
#define NEDGES 1600000
#define NR     100096   // 782 * 128, padded row count for GEMM tiles
#define NGRAPH 512
#define NBLK_SCAN 391   // ceil(100000/256)

typedef __attribute__((ext_vector_type(8))) __bf16 bf16x8;
typedef __attribute__((ext_vector_type(4))) float f32x4;

__device__ __forceinline__ float b2f(unsigned int u16) {
    union { float f; unsigned int i; } v; v.i = (u16 & 0xffffu) << 16; return v.f;
}
__device__ __forceinline__ unsigned short f2b(float f) {
    union { float f; unsigned int i; } v; v.f = f;
    unsigned int u = (v.i + 0x7fffu + ((v.i >> 16) & 1u)) >> 16;
    return (unsigned short)u;
}

// ---------------- CSR build ----------------
__global__ void hist_deg(const int* __restrict__ dst, int* __restrict__ deg) {
    int i = blockIdx.x * blockDim.x + threadIdx.x;
    int stride = gridDim.x * blockDim.x;
    for (; i < NEDGES; i += stride) atomicAdd(&deg[dst[i]], 1);
}

__global__ void scan_k1(const int* __restrict__ deg, int* __restrict__ bsum) {
    __shared__ int sm[256];
    int gid = blockIdx.x * 256 + threadIdx.x;
    sm[threadIdx.x] = (gid < NNODES) ? deg[gid] : 0;
    __syncthreads();
    for (int off = 128; off > 0; off >>= 1) {
        if (threadIdx.x < off) sm[threadIdx.x] += sm[threadIdx.x + off];
        __syncthreads();
    }
    if (threadIdx.x == 0) bsum[blockIdx.x] = sm[0];
}

__global__ void scan_k2(const int* __restrict__ bsum, int* __restrict__ boff, int nb) {
    __shared__ int sm[512];
    int t = threadIdx.x;
    sm[t] = (t < nb) ? bsum[t] : 0;
    __syncthreads();
    for (int off = 1; off < 512; off <<= 1) {
        int v = (t >= off) ? sm[t - off] : 0;
        __syncthreads();
        sm[t] += v;
        __syncthreads();
    }
    if (t < nb) boff[t] = (t == 0) ? 0 : sm[t - 1];
}

__global__ void scan_k3(const int* __restrict__ deg, const int* __restrict__ boff,
                        int* __restrict__ rowptr, int* __restrict__ cursor) {
    __shared__ int sm[256];
    int t = threadIdx.x, gid = blockIdx.x * 256 + t;
    int v = (gid < NNODES) ? deg[gid] : 0;
    sm[t] = v;
    __syncthreads();
    for (int off = 1; off < 256; off <<= 1) {
        int u = (t >= off) ? sm[t - off] : 0;
        __syncthreads();
        sm[t] += u;
        __syncthreads();
    }
    int incl = sm[t];
    int base = boff[blockIdx.x];
    if (gid < NNODES) {
        rowptr[gid] = base + incl - v;
        cursor[gid] = base + incl - v;
    }
    if (gid == NNODES - 1) rowptr[NNODES] = base + incl;
}

__global__ void scatter_edges(const int* __restrict__ src, const int* __restrict__ dst,
                              int* __restrict__ cursor, int* __restrict__ csr) {
    int i = blockIdx.x * blockDim.x + threadIdx.x;
    int stride = gridDim.x * blockDim.x;
    for (; i < NEDGES; i += stride) {
        int d = dst[i];
        int p = atomicAdd(&cursor[d], 1);
        csr[p] = src[i];
    }
}

// ---------------- aggregation: zf[i] = h[i] + sum_{j in CSR(i)} h[j] ----------------
__global__ __launch_bounds__(256) void agg_gather(const unsigned short* __restrict__ hb,
                                                  const int* __restrict__ rowptr,
                                                  const int* __restrict__ csr,
                                                  float* __restrict__ zf) {
    int wid = threadIdx.x >> 6, lane = threadIdx.x & 63;
    int node = blockIdx.x * 4 + wid;
    if (node >= NNODES) return;
    const unsigned int* hu = (const unsigned int*)hb;   // 2 bf16 per uint
    unsigned int own = hu[node * 64 + lane];
    float a0 = b2f(own), a1 = b2f(own >> 16);
    int s = rowptr[node], e = rowptr[node + 1];
    for (int base = s; base < e; base += 64) {
        int m = e - base; if (m > 64) m = 64;
        int idx = (lane < m) ? csr[base + lane] : 0;
        for (int i = 0; i < m; ++i) {
            int j = __shfl(idx, i);
            unsigned int v = hu[j * 64 + lane];
            a0 += b2f(v);
            a1 += b2f(v >> 16);
        }
    }
    float2 r; r.x = a0; r.y = a1;
    *reinterpret_cast<float2*>(zf + node * 128 + lane * 2) = r;
}

// ---------------- GEMM: out[r, j] = act( sum_k A[r,k] * W[j,k] + bias[j] ) ----------------
// MODE: 0 = bias only, 1 = bias+relu, 2 = bias, *bn_scale, +beta, relu
template <int SRC_F32, int MODE>
__global__ __launch_bounds__(256) void gemm128(const void* __restrict__ Asrc, int src_rows,
                                               const float* __restrict__ W,
                                               const float* __restrict__ bias,
                                               const float* __restrict__ gamma,
                                               const float* __restrict__ beta,
                                               unsigned short* __restrict__ Out) {
    __shared__ unsigned short lsA[128 * 128];
    __shared__ unsigned short lsB[128 * 128];
    const int tid = threadIdx.x;
    const int blockRow = blockIdx.x * 128;

    // stage W (f32 -> bf16, swizzled): element (j,k) at byte j*256 + ((2k)^((j&7)<<4))
    for (int it = 0; it < 16; ++it) {
        int fidx = it * 256 + tid;          // float4 index, 4096 total
        int row = fidx >> 5;                // 32 float4 per row
        int c4 = (fidx & 31) * 4;           // starting col
        float4 v = reinterpret_cast<const float4*>(W)[fidx];
        int boff = row * 256 + ((c4 * 2) ^ ((row & 7) << 4));
        unsigned short* p = (unsigned short*)((char*)lsB + boff);
        p[0] = f2b(v.x); p[1] = f2b(v.y); p[2] = f2b(v.z); p[3] = f2b(v.w);
    }
    // stage A
    if (SRC_F32) {
        const float* A = (const float*)Asrc;
        for (int it = 0; it < 16; ++it) {
            int fidx = it * 256 + tid;
            int row = fidx >> 5;
            int c4 = (fidx & 31) * 4;
            int gr = blockRow + row; if (gr > src_rows - 1) gr = src_rows - 1;
            float4 v = *reinterpret_cast<const float4*>(A + (size_t)gr * 128 + c4);
            int boff = row * 256 + ((c4 * 2) ^ ((row & 7) << 4));
            unsigned short* p = (unsigned short*)((char*)lsA + boff);
            p[0] = f2b(v.x); p[1] = f2b(v.y); p[2] = f2b(v.z); p[3] = f2b(v.w);
        }
    } else {
        const unsigned short* A = (const unsigned short*)Asrc;
        for (int it = 0; it < 8; ++it) {
            int idx = it * 256 + tid;       // 16B-unit index, 2048 total
            int row = idx >> 4;
            int u = idx & 15;
            int gr = blockRow + row; if (gr > src_rows - 1) gr = src_rows - 1;
            uint4 v = *reinterpret_cast<const uint4*>(A + (size_t)gr * 128 + u * 8);
            int boff = row * 256 + ((u * 16) ^ ((row & 7) << 4));
            *reinterpret_cast<uint4*>((char*)lsA + boff) = v;
        }
    }
    __syncthreads();

    const int lane = tid & 63;
    const int w = tid >> 6;
    const int wr = w >> 1, wc = w & 1;

    f32x4 acc[4][4];
    f32x4 zv = {0.f, 0.f, 0.f, 0.f};
#pragma unroll
    for (int m = 0; m < 4; ++m)
#pragma unroll
        for (int n = 0; n < 4; ++n) acc[m][n] = zv;

#pragma unroll
    for (int ks = 0; ks < 4; ++ks) {
        int kbb = ks * 64 + ((lane >> 4) << 4);   // byte offset of this lane-group's k-slice
        bf16x8 af[4], bfr[4];
#pragma unroll
        for (int m = 0; m < 4; ++m) {
            int ar = wr * 64 + m * 16 + (lane & 15);
            af[m] = *reinterpret_cast<const bf16x8*>((char*)lsA + ar * 256 + (kbb ^ ((ar & 7) << 4)));
        }
#pragma unroll
        for (int n = 0; n < 4; ++n) {
            int bc = wc * 64 + n * 16 + (lane & 15);
            bfr[n] = *reinterpret_cast<const bf16x8*>((char*)lsB + bc * 256 + (kbb ^ ((bc & 7) << 4)));
        }
#pragma unroll
        for (int m = 0; m < 4; ++m)
#pragma unroll
            for (int n = 0; n < 4; ++n)
                acc[m][n] = __builtin_amdgcn_mfma_f32_16x16x32_bf16(af[m], bfr[n], acc[m][n], 0, 0, 0);
    }

#pragma unroll
    for (int n = 0; n < 4; ++n) {
        int col = wc * 64 + n * 16 + (lane & 15);
        float bb = bias[col];
        float sc = 1.f, bt = 0.f;
        if (MODE == 2) { sc = gamma[col] * rsqrtf(1.0f + 1e-5f); bt = beta[col]; }
#pragma unroll
        for (int m = 0; m < 4; ++m) {
            int r0 = blockRow + wr * 64 + m * 16 + ((lane >> 4) << 2);
#pragma unroll
            for (int r = 0; r < 4; ++r) {
                float v = acc[m][n][r] + bb;
                if (MODE == 2) v = v * sc + bt;
                if (MODE >= 1) v = fmaxf(v, 0.f);
                Out[(size_t)(r0 + r) * 128 + col] = f2b(v);
            }
        }
    }
}

// ---------------- segment sum over sorted batch ----------------
__global__ __launch_bounds__(128) void segsum(const unsigned short* __restrict__ hf,
                                              const int* __restrict__ batch,
                                              float* __restrict__ out) {
    int g = blockIdx.x, f = threadIdx.x;
    int lo = 0, hi = NNODES;
    while (lo < hi) { int mid = (lo + hi) >> 1; if (batch[mid] < g) lo = mid + 1; else hi = mid; }
    int s = lo;
    lo = 0; hi = NNODES;
    while (lo < hi) { int mid = (lo + hi) >> 1; if (batch[mid] < g + 1) lo = mid + 1; else hi = mid; }
    int e = lo;
    float acc = 0.f;
    for (int n = s; n < e; ++n) acc += b2f(hf[(size_t)n * 128 + f]);
    out[(size_t)g * 128 + f] = acc;
}

extern "C" void kernel_launch(void* const* d_in, const int* in_sizes, int n_in,
                              void* d_out, int out_size, void* d_ws, size_t ws_size,
                              hipStream_t stream) {
    const float* x     = (const float*)d_in[0];
    const int*   ei    = (const int*)d_in[1];
    const int*   batch = (const int*)d_in[2];
    const float* t1w   = (const float*)d_in[3];
    const float* t1b   = (const float*)d_in[4];
    const float* t2w   = (const float*)d_in[5];
    const float* t2b   = (const float*)d_in[6];
    const float* W1    = (const float*)d_in[7];
    const float* b1    = (const float*)d_in[8];
    const float* gamma = (const float*)d_in[9];
    const float* beta  = (const float*)d_in[10];
    const float* W2    = (const float*)d_in[11];
    const float* b2    = (const float*)d_in[12];
    float* out = (float*)d_out;

    char* ws = (char*)d_ws;
    size_t off = 0;
    auto alloc = [&](size_t bytes) -> void* {
        off = (off + 511) & ~size_t(511);
        void* p = ws + off;
        off += bytes;
        return p;
    };
    unsigned short* hbA = (unsigned short*)alloc((size_t)NR * 128 * 2);
    unsigned short* hbB = (unsigned short*)alloc((size_t)NR * 128 * 2);
    float* zf           = (float*)alloc((size_t)NR * 128 * 4);
    int* deg            = (int*)alloc((size_t)(NNODES + 1) * 4);
    int* rowptr         = (int*)alloc((size_t)(NNODES + 1) * 4);
    int* cursor         = (int*)alloc((size_t)NNODES * 4);
    int* bsum           = (int*)alloc(512 * 4);
    int* boff           = (int*)alloc(512 * 4);
    int* csr            = (int*)alloc((size_t)NEDGES * 4);

    const int* esrc = ei;
    const int* edst = ei + NEDGES;

    // CSR build (per launch; ws is re-poisoned each call)
    hipMemsetAsync(deg, 0, (size_t)NNODES * 4, stream);
    hist_deg<<<1024, 256, 0, stream>>>(edst, deg);
    scan_k1<<<NBLK_SCAN, 256, 0, stream>>>(deg, bsum);
    scan_k2<<<1, 512, 0, stream>>>(bsum, boff, NBLK_SCAN);
    scan_k3<<<NBLK_SCAN, 256, 0, stream>>>(deg, boff, rowptr, cursor);
    scatter_edges<<<1024, 256, 0, stream>>>(esrc, edst, cursor, csr);

    // h = relu(x @ t1_w^T + t1_b)
    gemm128<1, 1><<<NR / 128, 256, 0, stream>>>(x, NNODES, t1w, t1b, nullptr, nullptr, hbA);

    for (int l = 0; l < 3; ++l) {
        agg_gather<<<25000, 256, 0, stream>>>(hbA, rowptr, csr, zf);
        gemm128<1, 2><<<NR / 128, 256, 0, stream>>>(zf, NR, W1 + (size_t)l * 16384, b1 + l * 128,
                                                    gamma + l * 128, beta + l * 128, hbB);
        gemm128<0, 0><<<NR / 128, 256, 0, stream>>>(hbB, NR, W2 + (size_t)l * 16384, b2 + l * 128,
                                                    nullptr, nullptr, hbA);
    }
    // final transform + graph pooling
    gemm128<0, 0><<<NR / 128, 256, 0, stream>>>(hbA, NR, t2w, t2b, nullptr, nullptr, hbB);
    segsum<<<NGRAPH, 128, 0, stream>>>(hbB, batch, out);
}

// Round 2
// 718.118 us; speedup vs baseline: 1.1319x; 1.1319x over previous
//
#include <hip/hip_runtime.h>
#include <hip/hip_bf16.h>

#define NNODES 100000
#define NEDGES 1600000
#define NR     100096   // 782 * 128, padded row count for GEMM tiles
#define NGRAPH 512
#define NB     782      // buckets of 128 dst nodes
#define NGRP   8        // per-XCD-ish groups for binning
#define BIN_GRID 512    // must be same for bin_hist and bin_scatter

typedef __attribute__((ext_vector_type(8))) __bf16 bf16x8;
typedef __attribute__((ext_vector_type(4))) float f32x4;

__device__ __forceinline__ float b2f(unsigned int u16) {
    union { float f; unsigned int i; } v; v.i = (u16 & 0xffffu) << 16; return v.f;
}
__device__ __forceinline__ unsigned short f2b(float f) {
    union { float f; unsigned int i; } v; v.f = f;
    unsigned int u = (v.i + 0x7fffu + ((v.i >> 16) & 1u)) >> 16;
    return (unsigned short)u;
}

// ---------------- CSR build via bucket binning ----------------
// bucket b = dst>>7 (128 nodes each). Edges binned (bucket-major, group-minor)
// so each bucket's edges are contiguous; csr writes are then block-local.

__global__ __launch_bounds__(256) void bin_hist(const int* __restrict__ dst,
                                                int* __restrict__ bcnt) {
    __shared__ int lh[NB];
    int g = blockIdx.x & (NGRP - 1);
    for (int i = threadIdx.x; i < NB; i += 256) lh[i] = 0;
    __syncthreads();
    for (int i = blockIdx.x * 256 + threadIdx.x; i < NEDGES; i += BIN_GRID * 256)
        atomicAdd(&lh[dst[i] >> 7], 1);
    __syncthreads();
    for (int i = threadIdx.x; i < NB; i += 256) {
        int v = lh[i];
        if (v) atomicAdd(&bcnt[i * NGRP + g], v);
    }
}

__global__ __launch_bounds__(1024) void bucket_scan(const int* __restrict__ bcnt,
                                                    int* __restrict__ cursor,
                                                    int* __restrict__ boff) {
    __shared__ int vals[7168];
    __shared__ int lsum[1024];
    const int M = NB * NGRP;   // 6256
    const int CH = 7;
    int t = threadIdx.x;
    int base = t * CH;
    int local = 0;
    for (int k = 0; k < CH; ++k) {
        int i = base + k;
        int v = (i < M) ? bcnt[i] : 0;
        vals[i] = v;
        local += v;
    }
    lsum[t] = local;
    __syncthreads();
    for (int off = 1; off < 1024; off <<= 1) {
        int v = (t >= off) ? lsum[t - off] : 0;
        __syncthreads();
        lsum[t] += v;
        __syncthreads();
    }
    int run = (t == 0) ? 0 : lsum[t - 1];
    for (int k = 0; k < CH; ++k) {
        int i = base + k;
        int v = vals[i];
        vals[i] = run;                  // exclusive prefix
        if (i < M) cursor[i] = run;
        run += v;
    }
    __syncthreads();
    for (int b = t; b < NB; b += 1024) boff[b] = vals[b * NGRP];
    if (t == 0) boff[NB] = NEDGES;
}

__global__ __launch_bounds__(256) void bin_scatter(const int* __restrict__ src,
                                                   const int* __restrict__ dst,
                                                   int* __restrict__ cursor,
                                                   unsigned int* __restrict__ binned) {
    int g = blockIdx.x & (NGRP - 1);
    for (int i = blockIdx.x * 256 + threadIdx.x; i < NEDGES; i += BIN_GRID * 256) {
        int d = dst[i];
        int b = d >> 7;
        int p = atomicAdd(&cursor[b * NGRP + g], 1);
        binned[p] = (unsigned int)src[i] | ((unsigned int)(d & 127) << 17);
    }
}

__global__ __launch_bounds__(256) void csr_build(const int* __restrict__ boff,
                                                 const unsigned int* __restrict__ binned,
                                                 int* __restrict__ rowptr,
                                                 int* __restrict__ csr) {
    __shared__ int lhist[128], lscan[128], lcnt[128];
    int b = blockIdx.x, tid = threadIdx.x;
    int s = boff[b], e = boff[b + 1];
    if (tid < 128) { lhist[tid] = 0; lcnt[tid] = 0; }
    __syncthreads();
    for (int i = s + tid; i < e; i += 256)
        atomicAdd(&lhist[(binned[i] >> 17) & 127], 1);
    __syncthreads();
    if (tid < 128) lscan[tid] = lhist[tid];
    __syncthreads();
    for (int off = 1; off < 128; off <<= 1) {
        int v = (tid < 128 && tid >= off) ? lscan[tid - off] : 0;
        __syncthreads();
        if (tid < 128) lscan[tid] += v;
        __syncthreads();
    }
    if (tid < 128) {
        int n = b * 128 + tid;
        if (n <= NNODES) rowptr[n] = s + lscan[tid] - lhist[tid];
    }
    __syncthreads();
    for (int i = s + tid; i < e; i += 256) {
        unsigned int v = binned[i];
        int dl = (v >> 17) & 127;
        int r = atomicAdd(&lcnt[dl], 1);
        csr[s + lscan[dl] - lhist[dl] + r] = (int)(v & 0x1FFFFu);
    }
}

// ---------------- aggregation: z[i] = h[i] + sum_{j in CSR(i)} h[j]  (bf16 out) ----------------
__global__ __launch_bounds__(256) void agg_gather(const unsigned short* __restrict__ hb,
                                                  const int* __restrict__ rowptr,
                                                  const int* __restrict__ csr,
                                                  unsigned int* __restrict__ zu) {
    int wid = threadIdx.x >> 6, lane = threadIdx.x & 63;
    int node = blockIdx.x * 4 + wid;
    if (node >= NNODES) return;
    const unsigned int* hu = (const unsigned int*)hb;   // 2 bf16 per uint
    unsigned int own = hu[node * 64 + lane];
    float a0 = b2f(own), a1 = b2f(own >> 16);
    int s = rowptr[node], e = rowptr[node + 1];
    for (int base = s; base < e; base += 64) {
        int m = e - base; if (m > 64) m = 64;
        int idx = (lane < m) ? csr[base + lane] : 0;
        for (int i = 0; i < m; ++i) {
            int j = __shfl(idx, i);
            unsigned int v = hu[j * 64 + lane];
            a0 += b2f(v);
            a1 += b2f(v >> 16);
        }
    }
    zu[node * 64 + lane] = (unsigned int)f2b(a0) | ((unsigned int)f2b(a1) << 16);
}

// ---------------- GEMM: out[r, j] = act( sum_k A[r,k] * W[j,k] + bias[j] ) ----------------
// MODE: 0 = bias only, 1 = bias+relu, 2 = bias, *bn_scale, +beta, relu
template <int SRC_F32, int MODE>
__global__ __launch_bounds__(256) void gemm128(const void* __restrict__ Asrc, int src_rows,
                                               const float* __restrict__ W,
                                               const float* __restrict__ bias,
                                               const float* __restrict__ gamma,
                                               const float* __restrict__ beta,
                                               unsigned short* __restrict__ Out) {
    __shared__ unsigned short lsA[128 * 128];
    __shared__ unsigned short lsB[128 * 128];
    const int tid = threadIdx.x;
    const int blockRow = blockIdx.x * 128;

    // stage W (f32 -> bf16, swizzled): element (j,k) at byte j*256 + ((2k)^((j&7)<<4))
    for (int it = 0; it < 16; ++it) {
        int fidx = it * 256 + tid;          // float4 index, 4096 total
        int row = fidx >> 5;                // 32 float4 per row
        int c4 = (fidx & 31) * 4;           // starting col
        float4 v = reinterpret_cast<const float4*>(W)[fidx];
        int boff = row * 256 + ((c4 * 2) ^ ((row & 7) << 4));
        unsigned short* p = (unsigned short*)((char*)lsB + boff);
        p[0] = f2b(v.x); p[1] = f2b(v.y); p[2] = f2b(v.z); p[3] = f2b(v.w);
    }
    // stage A
    if (SRC_F32) {
        const float* A = (const float*)Asrc;
        for (int it = 0; it < 16; ++it) {
            int fidx = it * 256 + tid;
            int row = fidx >> 5;
            int c4 = (fidx & 31) * 4;
            int gr = blockRow + row; if (gr > src_rows - 1) gr = src_rows - 1;
            float4 v = *reinterpret_cast<const float4*>(A + (size_t)gr * 128 + c4);
            int boff = row * 256 + ((c4 * 2) ^ ((row & 7) << 4));
            unsigned short* p = (unsigned short*)((char*)lsA + boff);
            p[0] = f2b(v.x); p[1] = f2b(v.y); p[2] = f2b(v.z); p[3] = f2b(v.w);
        }
    } else {
        const unsigned short* A = (const unsigned short*)Asrc;
        for (int it = 0; it < 8; ++it) {
            int idx = it * 256 + tid;       // 16B-unit index, 2048 total
            int row = idx >> 4;
            int u = idx & 15;
            int gr = blockRow + row; if (gr > src_rows - 1) gr = src_rows - 1;
            uint4 v = *reinterpret_cast<const uint4*>(A + (size_t)gr * 128 + u * 8);
            int boff = row * 256 + ((u * 16) ^ ((row & 7) << 4));
            *reinterpret_cast<uint4*>((char*)lsA + boff) = v;
        }
    }
    __syncthreads();

    const int lane = tid & 63;
    const int w = tid >> 6;
    const int wr = w >> 1, wc = w & 1;

    f32x4 acc[4][4];
    f32x4 zv = {0.f, 0.f, 0.f, 0.f};
#pragma unroll
    for (int m = 0; m < 4; ++m)
#pragma unroll
        for (int n = 0; n < 4; ++n) acc[m][n] = zv;

#pragma unroll
    for (int ks = 0; ks < 4; ++ks) {
        int kbb = ks * 64 + ((lane >> 4) << 4);   // byte offset of this lane-group's k-slice
        bf16x8 af[4], bfr[4];
#pragma unroll
        for (int m = 0; m < 4; ++m) {
            int ar = wr * 64 + m * 16 + (lane & 15);
            af[m] = *reinterpret_cast<const bf16x8*>((char*)lsA + ar * 256 + (kbb ^ ((ar & 7) << 4)));
        }
#pragma unroll
        for (int n = 0; n < 4; ++n) {
            int bc = wc * 64 + n * 16 + (lane & 15);
            bfr[n] = *reinterpret_cast<const bf16x8*>((char*)lsB + bc * 256 + (kbb ^ ((bc & 7) << 4)));
        }
#pragma unroll
        for (int m = 0; m < 4; ++m)
#pragma unroll
            for (int n = 0; n < 4; ++n)
                acc[m][n] = __builtin_amdgcn_mfma_f32_16x16x32_bf16(af[m], bfr[n], acc[m][n], 0, 0, 0);
    }

#pragma unroll
    for (int n = 0; n < 4; ++n) {
        int col = wc * 64 + n * 16 + (lane & 15);
        float bb = bias[col];
        float sc = 1.f, bt = 0.f;
        if (MODE == 2) { sc = gamma[col] * rsqrtf(1.0f + 1e-5f); bt = beta[col]; }
#pragma unroll
        for (int m = 0; m < 4; ++m) {
            int r0 = blockRow + wr * 64 + m * 16 + ((lane >> 4) << 2);
#pragma unroll
            for (int r = 0; r < 4; ++r) {
                float v = acc[m][n][r] + bb;
                if (MODE == 2) v = v * sc + bt;
                if (MODE >= 1) v = fmaxf(v, 0.f);
                Out[(size_t)(r0 + r) * 128 + col] = f2b(v);
            }
        }
    }
}

// ---------------- segment sum over sorted batch ----------------
__global__ __launch_bounds__(128) void segsum(const unsigned short* __restrict__ hf,
                                              const int* __restrict__ batch,
                                              float* __restrict__ out) {
    int g = blockIdx.x, f = threadIdx.x;
    int lo = 0, hi = NNODES;
    while (lo < hi) { int mid = (lo + hi) >> 1; if (batch[mid] < g) lo = mid + 1; else hi = mid; }
    int s = lo;
    lo = 0; hi = NNODES;
    while (lo < hi) { int mid = (lo + hi) >> 1; if (batch[mid] < g + 1) lo = mid + 1; else hi = mid; }
    int e = lo;
    float acc = 0.f;
    for (int n = s; n < e; ++n) acc += b2f(hf[(size_t)n * 128 + f]);
    out[(size_t)g * 128 + f] = acc;
}

extern "C" void kernel_launch(void* const* d_in, const int* in_sizes, int n_in,
                              void* d_out, int out_size, void* d_ws, size_t ws_size,
                              hipStream_t stream) {
    const float* x     = (const float*)d_in[0];
    const int*   ei    = (const int*)d_in[1];
    const int*   batch = (const int*)d_in[2];
    const float* t1w   = (const float*)d_in[3];
    const float* t1b   = (const float*)d_in[4];
    const float* t2w   = (const float*)d_in[5];
    const float* t2b   = (const float*)d_in[6];
    const float* W1    = (const float*)d_in[7];
    const float* b1    = (const float*)d_in[8];
    const float* gamma = (const float*)d_in[9];
    const float* beta  = (const float*)d_in[10];
    const float* W2    = (const float*)d_in[11];
    const float* b2    = (const float*)d_in[12];
    float* out = (float*)d_out;

    char* ws = (char*)d_ws;
    size_t off = 0;
    auto alloc = [&](size_t bytes) -> void* {
        off = (off + 511) & ~size_t(511);
        void* p = ws + off;
        off += bytes;
        return p;
    };
    unsigned short* hbA = (unsigned short*)alloc((size_t)NR * 128 * 2);
    unsigned short* hbB = (unsigned short*)alloc((size_t)NR * 128 * 2);
    unsigned int*   zb  = (unsigned int*)alloc((size_t)NR * 64 * 4);   // bf16x2 per uint
    int* rowptr         = (int*)alloc((size_t)(NNODES + 1) * 4);
    int* bcnt           = (int*)alloc((size_t)NB * NGRP * 4);
    int* cursor         = (int*)alloc((size_t)NB * NGRP * 4);
    int* boff           = (int*)alloc((size_t)(NB + 1) * 4);
    unsigned int* binned = (unsigned int*)alloc((size_t)NEDGES * 4);
    int* csr            = (int*)alloc((size_t)NEDGES * 4);

    const int* esrc = ei;
    const int* edst = ei + NEDGES;

    // CSR build (per launch; ws is re-poisoned each call)
    hipMemsetAsync(bcnt, 0, (size_t)NB * NGRP * 4, stream);
    bin_hist<<<BIN_GRID, 256, 0, stream>>>(edst, bcnt);
    bucket_scan<<<1, 1024, 0, stream>>>(bcnt, cursor, boff);
    bin_scatter<<<BIN_GRID, 256, 0, stream>>>(esrc, edst, cursor, binned);
    csr_build<<<NB, 256, 0, stream>>>(boff, binned, rowptr, csr);

    // h = relu(x @ t1_w^T + t1_b)
    gemm128<1, 1><<<NR / 128, 256, 0, stream>>>(x, NNODES, t1w, t1b, nullptr, nullptr, hbA);

    for (int l = 0; l < 3; ++l) {
        agg_gather<<<25000, 256, 0, stream>>>(hbA, rowptr, csr, zb);
        gemm128<0, 2><<<NR / 128, 256, 0, stream>>>(zb, NNODES, W1 + (size_t)l * 16384, b1 + l * 128,
                                                    gamma + l * 128, beta + l * 128, hbB);
        gemm128<0, 0><<<NR / 128, 256, 0, stream>>>(hbB, NNODES, W2 + (size_t)l * 16384, b2 + l * 128,
                                                    nullptr, nullptr, hbA);
    }
    // final transform + graph pooling
    gemm128<0, 0><<<NR / 128, 256, 0, stream>>>(hbA, NNODES, t2w, t2b, nullptr, nullptr, hbB);
    segsum<<<NGRAPH, 128, 0, stream>>>(hbB, batch, out);
}